// Round 7
// baseline (188.101 us; speedup 1.0000x reference)
//
#include <hip/hip_runtime.h>

// B=16, D=256, L=256, T=1000, K=3, DW=4, DC=2, CH=8

typedef short v8s __attribute__((ext_vector_type(8)));
typedef _Float16 v8h __attribute__((ext_vector_type(8)));
typedef float f4 __attribute__((ext_vector_type(4)));

__device__ __forceinline__ float bf2f(unsigned short h) {
  return __uint_as_float(((unsigned int)h) << 16);
}
__device__ __forceinline__ unsigned short f2bf(float f) {
  unsigned int u = __float_as_uint(f);
  u = (u + 0x7FFFu + ((u >> 16) & 1u)) >> 16;
  return (unsigned short)u;
}
__device__ __forceinline__ float swishf(float x) {
  return x * __builtin_amdgcn_rcpf(1.f + __expf(-x));
}

// =======================================================================
// K_PREP: level-0 work, branch on blockIdx.x  (unchanged)
// =======================================================================
__global__ __launch_bounds__(256) void k_prep(
    const float* __restrict__ dur, const float* __restrict__ ph,
    const float* __restrict__ liWw,
    const float* __restrict__ cvWw, const float* __restrict__ pjWw,
    const float* __restrict__ pjbw,
    const float* __restrict__ cvWc, const float* __restrict__ pjWc,
    const float* __restrict__ pjbc,
    float* __restrict__ sk, int* __restrict__ frame_len,
    unsigned short* __restrict__ Mb, float* __restrict__ bK,
    unsigned short* __restrict__ LWT, unsigned short* __restrict__ phT) {
  __shared__ float sm[32 * 33];
  int blk = blockIdx.x, tid = threadIdx.x;
  if (blk < 16) {
    int b = blk, l = tid;
    float d = dur[b * 256 + l];
    sm[l] = d;
    __syncthreads();
    for (int off = 1; off < 256; off <<= 1) {
      float v = (l >= off) ? sm[l - off] : 0.f;
      __syncthreads();
      sm[l] += v;
      __syncthreads();
    }
    sk[b * 256 + l] = sm[l] - d;
    if (l == 255) {
      int fl = (int)rintf(sm[255]);
      frame_len[b] = min(max(fl, 0), 1000);
    }
  } else if (blk < 64) {
    int x = blk - 16;
    int br = x / 24, ck = x % 24;
    int ch = ck / 3, k = ck % 3;
    const float* convW = br ? cvWc : cvWw;
    const float* projW = br ? pjWc : pjWw;
    const float* projb = br ? pjbc : pjbw;
    int d = tid;
    float a0 = 0.f, a1 = 0.f, a2 = 0.f, a3 = 0.f;
    for (int o = 0; o < 256; o += 4) {
      a0 += convW[ch * 768 + (o + 0) * 3 + k] * projW[(o + 0) * 256 + d];
      a1 += convW[ch * 768 + (o + 1) * 3 + k] * projW[(o + 1) * 256 + d];
      a2 += convW[ch * 768 + (o + 2) * 3 + k] * projW[(o + 2) * 256 + d];
      a3 += convW[ch * 768 + (o + 3) * 3 + k] * projW[(o + 3) * 256 + d];
    }
    Mb[(br * 24 + ck) * 256 + d] = f2bf((a0 + a1) + (a2 + a3));
    if (tid < 64) {
      float pb = 0.f;
      for (int o = tid; o < 256; o += 64)
        pb += convW[ch * 768 + o * 3 + k] * projb[o];
#pragma unroll
      for (int off = 1; off < 64; off <<= 1) pb += __shfl_xor(pb, off);
      if (tid == 0) bK[br * 24 + ck] = pb;
    }
  } else if (blk < 320) {
    int idx = blk - 64;
    int kt = idx & 31, ot = idx >> 5;
    int tx = tid & 31, ty = tid >> 5;
#pragma unroll
    for (int r = 0; r < 4; r++) {
      int row = ty + r * 8;
      sm[row * 33 + tx] = liWw[(size_t)(kt * 32 + row) * 256 + ot * 32 + tx];
    }
    __syncthreads();
#pragma unroll
    for (int r = 0; r < 4; r++) {
      int row = ty + r * 8;
      LWT[(size_t)(ot * 32 + row) * 1024 + kt * 32 + tx] =
          f2bf(sm[tx * 33 + row]);
    }
  } else {
    int idx = blk - 320;
    int ht = idx & 7, lt = (idx >> 3) & 7, b = idx >> 6;
    int tx = tid & 31, ty = tid >> 5;
#pragma unroll
    for (int r = 0; r < 4; r++) {
      int row = ty + r * 8;
      sm[row * 33 + tx] =
          ph[(size_t)b * 65536 + (size_t)(ht * 32 + row) * 256 + lt * 32 + tx];
    }
    __syncthreads();
#pragma unroll
    for (int r = 0; r < 4; r++) {
      int row = ty + r * 8;
      phT[(size_t)b * 65536 + (size_t)(lt * 32 + row) * 256 + ht * 32 + tx] =
          f2bf(sm[tx * 33 + row]);
    }
  }
}

// =======================================================================
// K_CONVG: unchanged from round 6
// =======================================================================
__global__ __launch_bounds__(256) void k_convG(
    const unsigned short* __restrict__ phT, const unsigned short* __restrict__ Mb,
    const float* __restrict__ bK, const float* __restrict__ cvbw,
    const float* __restrict__ cvbc, const float* __restrict__ dur,
    const float* __restrict__ sk, const float* __restrict__ mlpWw,
    const float* __restrict__ mlpbw, const float* __restrict__ mlpWc,
    const float* __restrict__ mlpbc, const unsigned short* __restrict__ LWT,
    float* __restrict__ Lbw, float* __restrict__ Laux,
    float* __restrict__ maxAb, _Float16* __restrict__ G) {
  __shared__ __align__(16) float C[256 * 49];
  __shared__ float redm[4][4];
  int blk = blockIdx.x;
  int tid = threadIdx.x, wave = tid >> 6, lane = tid & 63;
  int quad = lane >> 4, col = lane & 15;
  if (blk < 16) {
    int b = blk;
    int l0 = wave * 64;
    const unsigned short* Ab = phT + (size_t)b * 65536;
    f4 acc[4][3] = {};
#pragma unroll
    for (int k0 = 0; k0 < 256; k0 += 32) {
      v8s af[4], bf[3];
#pragma unroll
      for (int lt = 0; lt < 4; lt++)
        af[lt] = *(const v8s*)(Ab + (size_t)(l0 + lt * 16 + col) * 256 + k0 + quad * 8);
#pragma unroll
      for (int ct = 0; ct < 3; ct++)
        bf[ct] = *(const v8s*)(Mb + (size_t)(ct * 16 + col) * 256 + k0 + quad * 8);
#pragma unroll
      for (int lt = 0; lt < 4; lt++)
#pragma unroll
        for (int ct = 0; ct < 3; ct++)
          acc[lt][ct] = __builtin_amdgcn_mfma_f32_16x16x32_bf16(af[lt], bf[ct],
                                                                acc[lt][ct], 0, 0, 0);
    }
#pragma unroll
    for (int lt = 0; lt < 4; lt++)
#pragma unroll
      for (int ct = 0; ct < 3; ct++)
#pragma unroll
        for (int r = 0; r < 4; r++)
          C[(l0 + lt * 16 + quad * 4 + r) * 49 + ct * 16 + col] = acc[lt][ct][r];
    __syncthreads();
    int l = tid;
    float dv = dur[b * 256 + l];
    bool vld = (dv != 0.f);
    float hv[2][8];
#pragma unroll
    for (int br = 0; br < 2; br++) {
      const float* convb = br ? cvbc : cvbw;
#pragma unroll
      for (int ch = 0; ch < 8; ch++) {
        int ck = br * 24 + ch * 3;
        float v = convb[ch] + bK[ck + 1] + C[l * 49 + ck + 1];
        if (l > 0) v += bK[ck + 0] + C[(l - 1) * 49 + ck + 0];
        if (l < 255) v += bK[ck + 2] + C[(l + 1) * 49 + ck + 2];
        hv[br][ch] = vld ? swishf(v) : 0.f;
      }
    }
    float skl = sk[b * 256 + l];
    float A[4];
#pragma unroll
    for (int q = 0; q < 4; q++) {
      float a = mlpbw[q] + dv * mlpWw[4 + q] - skl * mlpWw[q];
#pragma unroll
      for (int ch = 0; ch < 8; ch++) a += hv[0][ch] * mlpWw[(2 + ch) * 4 + q];
      A[q] = vld ? a : -1e30f;
    }
    float bb0 = mlpbc[0] + dv * mlpWc[2] - skl * mlpWc[0];
    float bb1 = mlpbc[1] + dv * mlpWc[3] - skl * mlpWc[1];
#pragma unroll
    for (int ch = 0; ch < 8; ch++) {
      bb0 += hv[1][ch] * mlpWc[(2 + ch) * 2 + 0];
      bb1 += hv[1][ch] * mlpWc[(2 + ch) * 2 + 1];
    }
    float4 Av = {A[0], A[1], A[2], A[3]};
    ((float4*)Lbw)[b * 256 + l] = Av;
    float4 Xv = {bb0, bb1, vld ? 1.f : 0.f, 0.f};
    ((float4*)Laux)[b * 256 + l] = Xv;
    float m0 = A[0], m1 = A[1], m2 = A[2], m3 = A[3];
#pragma unroll
    for (int off = 1; off < 64; off <<= 1) {
      m0 = fmaxf(m0, __shfl_xor(m0, off));
      m1 = fmaxf(m1, __shfl_xor(m1, off));
      m2 = fmaxf(m2, __shfl_xor(m2, off));
      m3 = fmaxf(m3, __shfl_xor(m3, off));
    }
    if (lane == 0) {
      redm[wave][0] = m0;
      redm[wave][1] = m1;
      redm[wave][2] = m2;
      redm[wave][3] = m3;
    }
    __syncthreads();
    if (tid < 4)
      maxAb[b * 4 + tid] = fmaxf(fmaxf(redm[0][tid], redm[1][tid]),
                                 fmaxf(redm[2][tid], redm[3][tid]));
  } else {
    int idx = blk - 16;
    int b = (idx & 7) * 2 + ((idx >> 3) & 1);
    int sub = idx >> 4;  // 0..31
    int q = sub >> 3, rem = sub & 7;
    int mo = (rem >> 2) * 128, nl = (rem & 3) * 64;
    int wm = (wave & 1) * 64, wn = (wave >> 1) * 32;
    const unsigned short* Ag = LWT + (size_t)q * 256;
    const unsigned short* Bg = phT + (size_t)b * 65536;
    size_t aoff[4], boff[2];
#pragma unroll
    for (int mt = 0; mt < 4; mt++)
      aoff[mt] = (size_t)(mo + wm + mt * 16 + col) * 1024 + quad * 8;
#pragma unroll
    for (int nt = 0; nt < 2; nt++)
      boff[nt] = (size_t)(nl + wn + nt * 16 + col) * 256 + quad * 8;

    v8s ra[2][4], rb[2][2];
#pragma unroll
    for (int c = 0; c < 2; c++) {
#pragma unroll
      for (int mt = 0; mt < 4; mt++)
        ra[c][mt] = *(const v8s*)(Ag + aoff[mt] + c * 32);
#pragma unroll
      for (int nt = 0; nt < 2; nt++)
        rb[c][nt] = *(const v8s*)(Bg + boff[nt] + c * 32);
    }
    f4 acc[4][2] = {};
#pragma unroll
    for (int s = 0; s < 8; s++) {
#pragma unroll
      for (int mt = 0; mt < 4; mt++)
#pragma unroll
        for (int nt = 0; nt < 2; nt++)
          acc[mt][nt] = __builtin_amdgcn_mfma_f32_16x16x32_bf16(
              ra[s & 1][mt], rb[s & 1][nt], acc[mt][nt], 0, 0, 0);
      if (s < 6) {
#pragma unroll
        for (int mt = 0; mt < 4; mt++)
          ra[s & 1][mt] = *(const v8s*)(Ag + aoff[mt] + (s + 2) * 32);
#pragma unroll
        for (int nt = 0; nt < 2; nt++)
          rb[s & 1][nt] = *(const v8s*)(Bg + boff[nt] + (s + 2) * 32);
      }
    }
    _Float16* Gb = G + (size_t)b * 262144 + q * 256;
#pragma unroll
    for (int mt = 0; mt < 4; mt++)
#pragma unroll
      for (int r = 0; r < 4; r++) {
        int orow = mo + wm + mt * 16 + quad * 4 + r;
#pragma unroll
        for (int nt = 0; nt < 2; nt++) {
          int lcol = nl + wn + nt * 16 + col;
          Gb[(size_t)orow * 1024 + lcol] = (_Float16)acc[mt][nt][r];
        }
      }
  }
}

// =======================================================================
// K_FUSE: producer/consumer wave specialization.
// 16 waves: waves 0-7 = softmax producers (64 rows x 1 q per pass),
// waves 8-15 = GEMM consumers (M=64, N=32/wave -> LDS af traffic halved).
// 4 single-q passes, double-buffered 32KB Asm; producers compute pass p+1
// while consumers multiply pass p. G prefetch 4-deep, rolls across passes.
// k-accumulation order (q0..q3 ascending) and all rounding points match
// round 6 exactly; only f32 reduction grouping differs (8-lane vs 16).
// =======================================================================
__global__ __launch_bounds__(1024, 4) void k_fuse(
    const float* __restrict__ Lbw, const float* __restrict__ Laux,
    const float* __restrict__ maxAb, const int* __restrict__ frame_len,
    const float* __restrict__ mlpWw, const float* __restrict__ mlpWc,
    const _Float16* __restrict__ G, const float* __restrict__ lwb,
    const float* __restrict__ lcb, const float* __restrict__ LC,
    float* __restrict__ out) {
  __shared__ __align__(16) _Float16 AsmB[2][64 * 32 * 8];  // 2 x 32 KB
  __shared__ __align__(16) float4 Lb4[272];                // padded l + (l>>4)
  __shared__ __align__(16) float4 Lx4[272];
  __shared__ float bias_s[256];
  __shared__ float lcs[8][256];
  __shared__ float wcs[64][8];

  int idx = blockIdx.x;
  int b = (idx & 7) * 2 + ((idx >> 3) & 1);
  int t0 = (idx >> 4) * 64;
  int tid = threadIdx.x, wave = tid >> 6, lane = tid & 63;
  int quad = lane >> 4, col = lane & 15;

  int fl = frame_len[b];
  if (t0 >= fl) {
    int o = tid & 255;
    float v = lwb[o] + lcb[o];
    for (int r = tid >> 8; r < 64; r += 4) {
      int t = t0 + r;
      if (t < 1000) out[((size_t)(b * 1000 + t)) * 256 + o] = v;
    }
    return;
  }

  if (tid < 256) {
    float4 av = ((const float4*)Lbw)[b * 256 + tid];
    float4 xv = ((const float4*)Laux)[b * 256 + tid];
    int li = tid + (tid >> 4);
    Lb4[li] = av;
    Lx4[li] = xv;
    bias_s[tid] = lwb[tid] + lcb[tid];
  }
  for (int i = tid; i < 2048; i += 1024) lcs[i >> 8][i & 255] = LC[i];

  float4 mx4 = ((const float4*)maxAb)[b];
  float mwA0 = mlpWw[0], mwA1 = mlpWw[1], mwA2 = mlpWw[2], mwA3 = mlpWw[3];
  float mc0 = mlpWc[0], mc1 = mlpWc[1];

  bool isProd = wave < 8;

  // producer-role constants
  int prow = (wave & 7) * 8 + (lane >> 3);  // softmax row 0..63
  int l_grp8 = lane & 7;                    // 8 lanes per row, 32 l's each
  int pt = t0 + prow;
  bool plive = pt < fl;
  float ptp1 = (float)(pt + 1);

  // consumer-role constants
  int wn = (wave & 7) * 32;  // 8 waves x 32 cols = 256
  const _Float16* GA =
      G + (size_t)b * 262144 + (size_t)(wn + col) * 1024 + quad * 8;
  const _Float16* GB = GA + (size_t)16 * 1024;
  f4 acc[4][2] = {};
  v8h rb4[4][2];

#define PRODUCE(P, BUF)                                                        \
  do {                                                                         \
    float mq = (P == 0) ? mwA0 : (P == 1) ? mwA1 : (P == 2) ? mwA2 : mwA3;     \
    float mxq = (P == 0) ? mx4.x : (P == 1) ? mx4.y : (P == 2) ? mx4.z : mx4.w;\
    float m = plive ? fmaxf(mxq + ptp1 * mq, 0.f) : 1e30f;                     \
    float s0 = 0.f, pw0 = 0.f, pw1 = 0.f;                                      \
    v8h e[4];                                                                  \
    _Pragma("unroll") for (int j = 0; j < 32; ++j) {                           \
      int l = l_grp8 * 32 + j;                                                 \
      int li = l + (l >> 4);                                                   \
      float4 A4 = Lb4[li];                                                     \
      float4 ax = Lx4[li];                                                     \
      float cp0 = swishf(ax.x + ptp1 * mc0);                                   \
      float cp1 = swishf(ax.y + ptp1 * mc1);                                   \
      float Aq = (P == 0) ? A4.x : (P == 1) ? A4.y : (P == 2) ? A4.z : A4.w;   \
      _Float16 eh = (_Float16)(__expf(swishf(Aq + ptp1 * mq) - m) * ax.z);     \
      e[j >> 3][j & 7] = eh;                                                   \
      float f = (float)eh;                                                     \
      s0 += f;                                                                 \
      pw0 += f * cp0;                                                          \
      pw1 += f * cp1;                                                          \
    }                                                                          \
    _Pragma("unroll") for (int off = 1; off < 8; off <<= 1) {                  \
      s0 += __shfl_xor(s0, off);                                               \
      pw0 += __shfl_xor(pw0, off);                                             \
      pw1 += __shfl_xor(pw1, off);                                             \
    }                                                                          \
    float iv = plive ? 1.0f / s0 : 0.f;                                        \
    if (l_grp8 == 0) {                                                         \
      wcs[prow][(P)*2 + 0] = pw0 * iv;                                         \
      wcs[prow][(P)*2 + 1] = pw1 * iv;                                         \
    }                                                                          \
    _Pragma("unroll") for (int cc = 0; cc < 4; ++cc) {                         \
      v8h w;                                                                   \
      _Pragma("unroll") for (int k = 0; k < 8; ++k)                            \
          w[k] = (_Float16)((float)e[cc][k] * iv);                             \
      int sl = (l_grp8 * 4 + cc) ^ (prow & 7);                                 \
      *(v8h*)&AsmB[BUF][((prow * 32) + sl) * 8] = w;                           \
    }                                                                          \
  } while (0)

#define CONSUME(P, BUF, NP)                                                    \
  do {                                                                         \
    const _Float16* gpa = GA + (P)*256;                                        \
    const _Float16* gpb = GB + (P)*256;                                        \
    __builtin_amdgcn_s_setprio(1);                                             \
    _Pragma("unroll") for (int s = 0; s < 8; ++s) {                            \
      v8h af[4];                                                               \
      _Pragma("unroll") for (int mt = 0; mt < 4; ++mt)                         \
          af[mt] = *(const v8h*)&AsmB[BUF][(((mt * 16 + col) * 32) +           \
                                            ((s * 4 + quad) ^ (col & 7))) *    \
                                           8];                                 \
      _Pragma("unroll") for (int mt = 0; mt < 4; ++mt) {                       \
        acc[mt][0] = __builtin_amdgcn_mfma_f32_16x16x32_f16(                   \
            af[mt], rb4[s & 3][0], acc[mt][0], 0, 0, 0);                       \
        acc[mt][1] = __builtin_amdgcn_mfma_f32_16x16x32_f16(                   \
            af[mt], rb4[s & 3][1], acc[mt][1], 0, 0, 0);                       \
      }                                                                        \
      if (s < 4) {                                                             \
        rb4[s][0] = *(const v8h*)(gpa + (s + 4) * 32);                         \
        rb4[s][1] = *(const v8h*)(gpb + (s + 4) * 32);                         \
      } else if ((NP) >= 0) {                                                  \
        rb4[s - 4][0] = *(const v8h*)(GA + (NP)*256 + (s - 4) * 32);           \
        rb4[s - 4][1] = *(const v8h*)(GB + (NP)*256 + (s - 4) * 32);           \
      }                                                                        \
    }                                                                          \
    __builtin_amdgcn_s_setprio(0);                                             \
  } while (0)

  __syncthreads();  // staging visible

  if (isProd) {
    PRODUCE(0, 0);
  } else {
#pragma unroll
    for (int c = 0; c < 4; ++c) {  // prefetch pass-0 chunks 0..3
      rb4[c][0] = *(const v8h*)(GA + c * 32);
      rb4[c][1] = *(const v8h*)(GB + c * 32);
    }
  }
  __syncthreads();  // buf0(q0) ready
  if (isProd) PRODUCE(1, 1);
  else        CONSUME(0, 0, 1);
  __syncthreads();  // buf1(q1) ready, buf0 free
  if (isProd) PRODUCE(2, 0);
  else        CONSUME(1, 1, 2);
  __syncthreads();  // buf0(q2) ready, buf1 free
  if (isProd) PRODUCE(3, 1);
  else        CONSUME(2, 0, 3);
  __syncthreads();  // buf1(q3) ready; all wcs written
  if (!isProd) {
    CONSUME(3, 1, -1);
    // epilogue (consumers own all 64 rows x their 32 cols)
#pragma unroll
    for (int mt = 0; mt < 4; ++mt)
#pragma unroll
      for (int r = 0; r < 4; ++r) {
        int lrow = mt * 16 + quad * 4 + r;
        int trow = t0 + lrow;
        if (trow < 1000) {
          float4 wa = *(const float4*)&wcs[lrow][0];
          float4 wb = *(const float4*)&wcs[lrow][4];
          float wcl[8] = {wa.x, wa.y, wa.z, wa.w, wb.x, wb.y, wb.z, wb.w};
#pragma unroll
          for (int nt = 0; nt < 2; ++nt) {
            int oc = wn + nt * 16 + col;
            float v = acc[mt][nt][r] + bias_s[oc];
#pragma unroll
            for (int jj = 0; jj < 8; ++jj) v = fmaf(wcl[jj], lcs[jj][oc], v);
            out[((size_t)(b * 1000 + trow)) * 256 + oc] = v;
          }
        }
      }
  }
#undef PRODUCE
#undef CONSUME
}

// ---------- launch ----------
extern "C" void kernel_launch(void* const* d_in, const int* in_sizes, int n_in,
                              void* d_out, int out_size, void* d_ws, size_t ws_size,
                              hipStream_t stream) {
  const float* dur  = (const float*)d_in[0];
  const float* ph   = (const float*)d_in[1];
  const float* pjWw = (const float*)d_in[3];
  const float* pjbw = (const float*)d_in[4];
  const float* cvWw = (const float*)d_in[5];
  const float* cvbw = (const float*)d_in[6];
  const float* mlWw = (const float*)d_in[7];
  const float* mlbw = (const float*)d_in[8];
  const float* liWw = (const float*)d_in[9];
  const float* libw = (const float*)d_in[10];
  const float* pjWc = (const float*)d_in[11];
  const float* pjbc = (const float*)d_in[12];
  const float* cvWc = (const float*)d_in[13];
  const float* cvbc = (const float*)d_in[14];
  const float* mlWc = (const float*)d_in[15];
  const float* mlbc = (const float*)d_in[16];
  const float* liWc = (const float*)d_in[17];
  const float* libc = (const float*)d_in[18];
  float* out = (float*)d_out;

  float* f = (float*)d_ws;
  size_t o = 0;
  float* sk = f + o;            o += 4096;
  int* fl = (int*)(f + o);      o += 16;
  float* bK = f + o;            o += 64;
  unsigned short* Mb = (unsigned short*)(f + o); o += 6144;
  float* Lbw = f + o;           o += 16384;   // [b][l] float4 MLP bases (w)
  float* Laux = f + o;          o += 16384;   // [b][l] {bb0, bb1, msk, -}
  float* mxA = f + o;           o += 64;      // [b][4] max_l A
  _Float16* G = (_Float16*)(f + o);              o += 2097152;  // 8.4 MB
  unsigned short* phT = (unsigned short*)(f + o); o += 524288;
  unsigned short* LWT = (unsigned short*)(f + o); o += 131072;

  k_prep<<<1344, 256, 0, stream>>>(dur, ph, liWw, cvWw, pjWw, pjbw, cvWc, pjWc,
                                   pjbc, sk, fl, Mb, bK, LWT, phT);
  k_convG<<<528, 256, 0, stream>>>(phT, Mb, bK, cvbw, cvbc, dur, sk, mlWw,
                                   mlbw, mlWc, mlbc, LWT, Lbw, Laux, mxA, G);
  k_fuse<<<256, 1024, 0, stream>>>(Lbw, Laux, mxA, fl, mlWw, mlWc, G, libw,
                                   libc, liWc, out);
}

// Round 8
// 168.417 us; speedup vs baseline: 1.1169x; 1.1169x over previous
//
#include <hip/hip_runtime.h>

// B=16, D=256, L=256, T=1000, K=3, DW=4, DC=2, CH=8

typedef short v8s __attribute__((ext_vector_type(8)));
typedef _Float16 v8h __attribute__((ext_vector_type(8)));
typedef float f4 __attribute__((ext_vector_type(4)));

__device__ __forceinline__ float bf2f(unsigned short h) {
  return __uint_as_float(((unsigned int)h) << 16);
}
__device__ __forceinline__ unsigned short f2bf(float f) {
  unsigned int u = __float_as_uint(f);
  u = (u + 0x7FFFu + ((u >> 16) & 1u)) >> 16;
  return (unsigned short)u;
}
__device__ __forceinline__ float swishf(float x) {
  return x * __builtin_amdgcn_rcpf(1.f + __expf(-x));
}

// =======================================================================
// K_PREP: level-0 work, branch on blockIdx.x  (round-6 version)
// =======================================================================
__global__ __launch_bounds__(256) void k_prep(
    const float* __restrict__ dur, const float* __restrict__ ph,
    const float* __restrict__ liWw,
    const float* __restrict__ cvWw, const float* __restrict__ pjWw,
    const float* __restrict__ pjbw,
    const float* __restrict__ cvWc, const float* __restrict__ pjWc,
    const float* __restrict__ pjbc,
    float* __restrict__ sk, int* __restrict__ frame_len,
    unsigned short* __restrict__ Mb, float* __restrict__ bK,
    unsigned short* __restrict__ LWT, unsigned short* __restrict__ phT) {
  __shared__ float sm[32 * 33];
  int blk = blockIdx.x, tid = threadIdx.x;
  if (blk < 16) {
    int b = blk, l = tid;
    float d = dur[b * 256 + l];
    sm[l] = d;
    __syncthreads();
    for (int off = 1; off < 256; off <<= 1) {
      float v = (l >= off) ? sm[l - off] : 0.f;
      __syncthreads();
      sm[l] += v;
      __syncthreads();
    }
    sk[b * 256 + l] = sm[l] - d;
    if (l == 255) {
      int fl = (int)rintf(sm[255]);
      frame_len[b] = min(max(fl, 0), 1000);
    }
  } else if (blk < 64) {
    int x = blk - 16;
    int br = x / 24, ck = x % 24;
    int ch = ck / 3, k = ck % 3;
    const float* convW = br ? cvWc : cvWw;
    const float* projW = br ? pjWc : pjWw;
    const float* projb = br ? pjbc : pjbw;
    int d = tid;
    float a0 = 0.f, a1 = 0.f, a2 = 0.f, a3 = 0.f;
    for (int o = 0; o < 256; o += 4) {
      a0 += convW[ch * 768 + (o + 0) * 3 + k] * projW[(o + 0) * 256 + d];
      a1 += convW[ch * 768 + (o + 1) * 3 + k] * projW[(o + 1) * 256 + d];
      a2 += convW[ch * 768 + (o + 2) * 3 + k] * projW[(o + 2) * 256 + d];
      a3 += convW[ch * 768 + (o + 3) * 3 + k] * projW[(o + 3) * 256 + d];
    }
    Mb[(br * 24 + ck) * 256 + d] = f2bf((a0 + a1) + (a2 + a3));
    if (tid < 64) {
      float pb = 0.f;
      for (int o = tid; o < 256; o += 64)
        pb += convW[ch * 768 + o * 3 + k] * projb[o];
#pragma unroll
      for (int off = 1; off < 64; off <<= 1) pb += __shfl_xor(pb, off);
      if (tid == 0) bK[br * 24 + ck] = pb;
    }
  } else if (blk < 320) {
    int idx = blk - 64;
    int kt = idx & 31, ot = idx >> 5;
    int tx = tid & 31, ty = tid >> 5;
#pragma unroll
    for (int r = 0; r < 4; r++) {
      int row = ty + r * 8;
      sm[row * 33 + tx] = liWw[(size_t)(kt * 32 + row) * 256 + ot * 32 + tx];
    }
    __syncthreads();
#pragma unroll
    for (int r = 0; r < 4; r++) {
      int row = ty + r * 8;
      LWT[(size_t)(ot * 32 + row) * 1024 + kt * 32 + tx] =
          f2bf(sm[tx * 33 + row]);
    }
  } else {
    int idx = blk - 320;
    int ht = idx & 7, lt = (idx >> 3) & 7, b = idx >> 6;
    int tx = tid & 31, ty = tid >> 5;
#pragma unroll
    for (int r = 0; r < 4; r++) {
      int row = ty + r * 8;
      sm[row * 33 + tx] =
          ph[(size_t)b * 65536 + (size_t)(ht * 32 + row) * 256 + lt * 32 + tx];
    }
    __syncthreads();
#pragma unroll
    for (int r = 0; r < 4; r++) {
      int row = ty + r * 8;
      phT[(size_t)b * 65536 + (size_t)(lt * 32 + row) * 256 + ht * 32 + tx] =
          f2bf(sm[tx * 33 + row]);
    }
  }
}

// =======================================================================
// K_CONVG: round-6 version (unchanged)
// =======================================================================
__global__ __launch_bounds__(256) void k_convG(
    const unsigned short* __restrict__ phT, const unsigned short* __restrict__ Mb,
    const float* __restrict__ bK, const float* __restrict__ cvbw,
    const float* __restrict__ cvbc, const float* __restrict__ dur,
    const float* __restrict__ sk, const float* __restrict__ mlpWw,
    const float* __restrict__ mlpbw, const float* __restrict__ mlpWc,
    const float* __restrict__ mlpbc, const unsigned short* __restrict__ LWT,
    float* __restrict__ Lbw, float* __restrict__ Laux,
    float* __restrict__ maxAb, _Float16* __restrict__ G) {
  __shared__ __align__(16) float C[256 * 49];
  __shared__ float redm[4][4];
  int blk = blockIdx.x;
  int tid = threadIdx.x, wave = tid >> 6, lane = tid & 63;
  int quad = lane >> 4, col = lane & 15;
  if (blk < 16) {
    int b = blk;
    int l0 = wave * 64;
    const unsigned short* Ab = phT + (size_t)b * 65536;
    f4 acc[4][3] = {};
#pragma unroll
    for (int k0 = 0; k0 < 256; k0 += 32) {
      v8s af[4], bf[3];
#pragma unroll
      for (int lt = 0; lt < 4; lt++)
        af[lt] = *(const v8s*)(Ab + (size_t)(l0 + lt * 16 + col) * 256 + k0 + quad * 8);
#pragma unroll
      for (int ct = 0; ct < 3; ct++)
        bf[ct] = *(const v8s*)(Mb + (size_t)(ct * 16 + col) * 256 + k0 + quad * 8);
#pragma unroll
      for (int lt = 0; lt < 4; lt++)
#pragma unroll
        for (int ct = 0; ct < 3; ct++)
          acc[lt][ct] = __builtin_amdgcn_mfma_f32_16x16x32_bf16(af[lt], bf[ct],
                                                                acc[lt][ct], 0, 0, 0);
    }
#pragma unroll
    for (int lt = 0; lt < 4; lt++)
#pragma unroll
      for (int ct = 0; ct < 3; ct++)
#pragma unroll
        for (int r = 0; r < 4; r++)
          C[(l0 + lt * 16 + quad * 4 + r) * 49 + ct * 16 + col] = acc[lt][ct][r];
    __syncthreads();
    int l = tid;
    float dv = dur[b * 256 + l];
    bool vld = (dv != 0.f);
    float hv[2][8];
#pragma unroll
    for (int br = 0; br < 2; br++) {
      const float* convb = br ? cvbc : cvbw;
#pragma unroll
      for (int ch = 0; ch < 8; ch++) {
        int ck = br * 24 + ch * 3;
        float v = convb[ch] + bK[ck + 1] + C[l * 49 + ck + 1];
        if (l > 0) v += bK[ck + 0] + C[(l - 1) * 49 + ck + 0];
        if (l < 255) v += bK[ck + 2] + C[(l + 1) * 49 + ck + 2];
        hv[br][ch] = vld ? swishf(v) : 0.f;
      }
    }
    float skl = sk[b * 256 + l];
    float A[4];
#pragma unroll
    for (int q = 0; q < 4; q++) {
      float a = mlpbw[q] + dv * mlpWw[4 + q] - skl * mlpWw[q];
#pragma unroll
      for (int ch = 0; ch < 8; ch++) a += hv[0][ch] * mlpWw[(2 + ch) * 4 + q];
      A[q] = vld ? a : -1e30f;
    }
    float bb0 = mlpbc[0] + dv * mlpWc[2] - skl * mlpWc[0];
    float bb1 = mlpbc[1] + dv * mlpWc[3] - skl * mlpWc[1];
#pragma unroll
    for (int ch = 0; ch < 8; ch++) {
      bb0 += hv[1][ch] * mlpWc[(2 + ch) * 2 + 0];
      bb1 += hv[1][ch] * mlpWc[(2 + ch) * 2 + 1];
    }
    float4 Av = {A[0], A[1], A[2], A[3]};
    ((float4*)Lbw)[b * 256 + l] = Av;
    float4 Xv = {bb0, bb1, vld ? 1.f : 0.f, 0.f};
    ((float4*)Laux)[b * 256 + l] = Xv;
    float m0 = A[0], m1 = A[1], m2 = A[2], m3 = A[3];
#pragma unroll
    for (int off = 1; off < 64; off <<= 1) {
      m0 = fmaxf(m0, __shfl_xor(m0, off));
      m1 = fmaxf(m1, __shfl_xor(m1, off));
      m2 = fmaxf(m2, __shfl_xor(m2, off));
      m3 = fmaxf(m3, __shfl_xor(m3, off));
    }
    if (lane == 0) {
      redm[wave][0] = m0;
      redm[wave][1] = m1;
      redm[wave][2] = m2;
      redm[wave][3] = m3;
    }
    __syncthreads();
    if (tid < 4)
      maxAb[b * 4 + tid] = fmaxf(fmaxf(redm[0][tid], redm[1][tid]),
                                 fmaxf(redm[2][tid], redm[3][tid]));
  } else {
    int idx = blk - 16;
    int b = (idx & 7) * 2 + ((idx >> 3) & 1);
    int sub = idx >> 4;  // 0..31
    int q = sub >> 3, rem = sub & 7;
    int mo = (rem >> 2) * 128, nl = (rem & 3) * 64;
    int wm = (wave & 1) * 64, wn = (wave >> 1) * 32;
    const unsigned short* Ag = LWT + (size_t)q * 256;
    const unsigned short* Bg = phT + (size_t)b * 65536;
    size_t aoff[4], boff[2];
#pragma unroll
    for (int mt = 0; mt < 4; mt++)
      aoff[mt] = (size_t)(mo + wm + mt * 16 + col) * 1024 + quad * 8;
#pragma unroll
    for (int nt = 0; nt < 2; nt++)
      boff[nt] = (size_t)(nl + wn + nt * 16 + col) * 256 + quad * 8;

    v8s ra[2][4], rb[2][2];
#pragma unroll
    for (int c = 0; c < 2; c++) {
#pragma unroll
      for (int mt = 0; mt < 4; mt++)
        ra[c][mt] = *(const v8s*)(Ag + aoff[mt] + c * 32);
#pragma unroll
      for (int nt = 0; nt < 2; nt++)
        rb[c][nt] = *(const v8s*)(Bg + boff[nt] + c * 32);
    }
    f4 acc[4][2] = {};
#pragma unroll
    for (int s = 0; s < 8; s++) {
#pragma unroll
      for (int mt = 0; mt < 4; mt++)
#pragma unroll
        for (int nt = 0; nt < 2; nt++)
          acc[mt][nt] = __builtin_amdgcn_mfma_f32_16x16x32_bf16(
              ra[s & 1][mt], rb[s & 1][nt], acc[mt][nt], 0, 0, 0);
      if (s < 6) {
#pragma unroll
        for (int mt = 0; mt < 4; mt++)
          ra[s & 1][mt] = *(const v8s*)(Ag + aoff[mt] + (s + 2) * 32);
#pragma unroll
        for (int nt = 0; nt < 2; nt++)
          rb[s & 1][nt] = *(const v8s*)(Bg + boff[nt] + (s + 2) * 32);
      }
    }
    _Float16* Gb = G + (size_t)b * 262144 + q * 256;
#pragma unroll
    for (int mt = 0; mt < 4; mt++)
#pragma unroll
      for (int r = 0; r < 4; r++) {
        int orow = mo + wm + mt * 16 + quad * 4 + r;
#pragma unroll
        for (int nt = 0; nt < 2; nt++) {
          int lcol = nl + wn + nt * 16 + col;
          Gb[(size_t)orow * 1024 + lcol] = (_Float16)acc[mt][nt][r];
        }
      }
  }
}

// =======================================================================
// K_FUSE: round-6 version (M=64, 16 waves, pass-1 softmax fused into
// GEMM(0)) with ONE change: non-temporal out stores (out is write-once,
// never re-read; keep G resident in L2 instead).
// =======================================================================
__global__ __launch_bounds__(1024, 4) void k_fuse(
    const float* __restrict__ Lbw, const float* __restrict__ Laux,
    const float* __restrict__ maxAb, const int* __restrict__ frame_len,
    const float* __restrict__ mlpWw, const float* __restrict__ mlpWc,
    const _Float16* __restrict__ G, const float* __restrict__ lwb,
    const float* __restrict__ lcb, const float* __restrict__ LC,
    float* __restrict__ out) {
  __shared__ __align__(16) _Float16 Asm[64 * 512];  // XOR-swizzled w tile (64 KB)
  __shared__ __align__(16) float4 Lb4[272];         // padded: l + (l>>4)
  __shared__ __align__(16) float4 Lx4[272];
  __shared__ float bias_s[256];
  __shared__ float lcs[8][256];
  __shared__ float wcs[64][8];

  int idx = blockIdx.x;
  int b = (idx & 7) * 2 + ((idx >> 3) & 1);
  int t0 = (idx >> 4) * 64;
  int tid = threadIdx.x, wave = tid >> 6, lane = tid & 63;
  int quad = lane >> 4, col = lane & 15;

  int fl = frame_len[b];
  if (t0 >= fl) {
    int o = tid & 255;
    float v = lwb[o] + lcb[o];
    for (int r = tid >> 8; r < 64; r += 4) {
      int t = t0 + r;
      if (t < 1000)
        __builtin_nontemporal_store(v, &out[((size_t)(b * 1000 + t)) * 256 + o]);
    }
    return;
  }

  if (tid < 256) {
    float4 av = ((const float4*)Lbw)[b * 256 + tid];
    float4 xv = ((const float4*)Laux)[b * 256 + tid];
    int li = tid + (tid >> 4);
    Lb4[li] = av;
    Lx4[li] = xv;
    bias_s[tid] = lwb[tid] + lcb[tid];
  }
  for (int i = tid; i < 2048; i += 1024) lcs[i >> 8][i & 255] = LC[i];

  float4 mx4 = ((const float4*)maxAb)[b];
  float mw0 = mlpWw[0], mw1 = mlpWw[1], mw2 = mlpWw[2], mw3 = mlpWw[3];
  float mc0 = mlpWc[0], mc1 = mlpWc[1];

  int l_grp = lane & 15;
  int row = wave * 4 + (lane >> 4);  // softmax row owned by this thread (0..63)
  int t = t0 + row;
  bool live = (t < fl);
  float tp1 = (float)(t + 1);
  int rsw = row & 7;
  int asw = col & 7;
  int wn = wave * 16;  // 16 waves x 16 cols
  f4 acc[4] = {};

  const _Float16* GA =
      G + (size_t)b * 262144 + (size_t)(wn + col) * 1024 + quad * 8;
  const _Float16* Gp0 = GA;        // pass 0 k-range
  const _Float16* Gp1 = GA + 512;  // pass 1 k-range

  __syncthreads();

  // ---------- pass-0 softmax (G0 prefetch in flight underneath) ----------
  v8h rb[4];
#pragma unroll
  for (int c = 0; c < 4; ++c) rb[c] = *(const v8h*)(Gp0 + c * 32);

  float m0a = live ? fmaxf(mx4.x + tp1 * mw0, 0.f) : 1e30f;
  float m1a = live ? fmaxf(mx4.y + tp1 * mw1, 0.f) : 1e30f;
  {
    float s0 = 0.f, s1 = 0.f, p00 = 0.f, p01 = 0.f, p10 = 0.f, p11 = 0.f;
    v8h e0[2], e1[2];
#pragma unroll
    for (int j = 0; j < 16; ++j) {
      int l = l_grp * 16 + j;
      int li = l + (l >> 4);
      float4 A4 = Lb4[li];
      float4 ax = Lx4[li];
      float cp0 = swishf(ax.x + tp1 * mc0);
      float cp1 = swishf(ax.y + tp1 * mc1);
      _Float16 eh0 = (_Float16)(__expf(swishf(A4.x + tp1 * mw0) - m0a) * ax.z);
      _Float16 eh1 = (_Float16)(__expf(swishf(A4.y + tp1 * mw1) - m1a) * ax.z);
      e0[j >> 3][j & 7] = eh0;
      e1[j >> 3][j & 7] = eh1;
      float f0 = (float)eh0, f1 = (float)eh1;
      s0 += f0;
      s1 += f1;
      p00 += f0 * cp0;
      p01 += f0 * cp1;
      p10 += f1 * cp0;
      p11 += f1 * cp1;
    }
#pragma unroll
    for (int off = 1; off < 16; off <<= 1) {
      s0 += __shfl_xor(s0, off);
      s1 += __shfl_xor(s1, off);
      p00 += __shfl_xor(p00, off);
      p01 += __shfl_xor(p01, off);
      p10 += __shfl_xor(p10, off);
      p11 += __shfl_xor(p11, off);
    }
    float iv0 = live ? 1.0f / s0 : 0.f;
    float iv1 = live ? 1.0f / s1 : 0.f;
    if (l_grp == 0) {
      wcs[row][0] = p00 * iv0;
      wcs[row][1] = p01 * iv0;
      wcs[row][2] = p10 * iv1;
      wcs[row][3] = p11 * iv1;
    }
#pragma unroll
    for (int c = 0; c < 2; ++c) {
      int sl = (l_grp * 2 + c) ^ rsw;
      v8h w0, w1;
#pragma unroll
      for (int k = 0; k < 8; ++k) {
        w0[k] = (_Float16)((float)e0[c][k] * iv0);
        w1[k] = (_Float16)((float)e1[c][k] * iv1);
      }
      *(v8h*)&Asm[(row * 64 + sl) * 8] = w0;
      *(v8h*)&Asm[(row * 64 + 32 + sl) * 8] = w1;
    }
  }
  __syncthreads();  // Asm(0) visible

  // ---------- fused region: GEMM(0) interleaved with pass-1 softmax ------
  float m0b = live ? fmaxf(mx4.z + tp1 * mw2, 0.f) : 1e30f;
  float m1b = live ? fmaxf(mx4.w + tp1 * mw3, 0.f) : 1e30f;
  float s0b = 0.f, s1b = 0.f, p00b = 0.f, p01b = 0.f, p10b = 0.f, p11b = 0.f;
  v8h e0b[2], e1b[2];
  __builtin_amdgcn_s_setprio(1);
#pragma unroll
  for (int s = 0; s < 16; ++s) {
    int slk = s * 4 + quad;
    v8h af[4];
#pragma unroll
    for (int mt = 0; mt < 4; ++mt)
      af[mt] = *(const v8h*)&Asm[((mt * 16 + col) * 64 + (slk ^ asw)) * 8];
#pragma unroll
    for (int mt = 0; mt < 4; ++mt)
      acc[mt] = __builtin_amdgcn_mfma_f32_16x16x32_f16(af[mt], rb[s & 3],
                                                       acc[mt], 0, 0, 0);
    if (s < 12) rb[s & 3] = *(const v8h*)(Gp0 + (s + 4) * 32);
    {  // pass-1 softmax, j == s  (independent VALU chain, hides under MFMA)
      int l = l_grp * 16 + s;
      int li = l + (l >> 4);
      float4 A4 = Lb4[li];
      float4 ax = Lx4[li];
      float cp0 = swishf(ax.x + tp1 * mc0);
      float cp1 = swishf(ax.y + tp1 * mc1);
      _Float16 eh0 = (_Float16)(__expf(swishf(A4.z + tp1 * mw2) - m0b) * ax.z);
      _Float16 eh1 = (_Float16)(__expf(swishf(A4.w + tp1 * mw3) - m1b) * ax.z);
      e0b[s >> 3][s & 7] = eh0;
      e1b[s >> 3][s & 7] = eh1;
      float f0 = (float)eh0, f1 = (float)eh1;
      s0b += f0;
      s1b += f1;
      p00b += f0 * cp0;
      p01b += f0 * cp1;
      p10b += f1 * cp0;
      p11b += f1 * cp1;
    }
  }
  __builtin_amdgcn_s_setprio(0);

  // pass-1 G prefetch in flight across the barriers below
  v8h rb1[4];
#pragma unroll
  for (int c = 0; c < 4; ++c) rb1[c] = *(const v8h*)(Gp1 + c * 32);

#pragma unroll
  for (int off = 1; off < 16; off <<= 1) {
    s0b += __shfl_xor(s0b, off);
    s1b += __shfl_xor(s1b, off);
    p00b += __shfl_xor(p00b, off);
    p01b += __shfl_xor(p01b, off);
    p10b += __shfl_xor(p10b, off);
    p11b += __shfl_xor(p11b, off);
  }
  float iv0b = live ? 1.0f / s0b : 0.f;
  float iv1b = live ? 1.0f / s1b : 0.f;

  __syncthreads();  // GEMM(0) done reading Asm

  if (l_grp == 0) {
    wcs[row][4] = p00b * iv0b;
    wcs[row][5] = p01b * iv0b;
    wcs[row][6] = p10b * iv1b;
    wcs[row][7] = p11b * iv1b;
  }
#pragma unroll
  for (int c = 0; c < 2; ++c) {
    int sl = (l_grp * 2 + c) ^ rsw;
    v8h w0, w1;
#pragma unroll
    for (int k = 0; k < 8; ++k) {
      w0[k] = (_Float16)((float)e0b[c][k] * iv0b);
      w1[k] = (_Float16)((float)e1b[c][k] * iv1b);
    }
    *(v8h*)&Asm[(row * 64 + sl) * 8] = w0;
    *(v8h*)&Asm[(row * 64 + 32 + sl) * 8] = w1;
  }
  __syncthreads();  // Asm(1) visible

  __builtin_amdgcn_s_setprio(1);
#pragma unroll
  for (int s = 0; s < 16; ++s) {
    int slk = s * 4 + quad;
    v8h af[4];
#pragma unroll
    for (int mt = 0; mt < 4; ++mt)
      af[mt] = *(const v8h*)&Asm[((mt * 16 + col) * 64 + (slk ^ asw)) * 8];
#pragma unroll
    for (int mt = 0; mt < 4; ++mt)
      acc[mt] = __builtin_amdgcn_mfma_f32_16x16x32_f16(af[mt], rb1[s & 3],
                                                       acc[mt], 0, 0, 0);
    if (s < 12) rb1[s & 3] = *(const v8h*)(Gp1 + (s + 4) * 32);
  }
  __builtin_amdgcn_s_setprio(0);

#pragma unroll
  for (int mt = 0; mt < 4; ++mt)
#pragma unroll
    for (int r = 0; r < 4; ++r) {
      int lrow = mt * 16 + quad * 4 + r;
      int trow = t0 + lrow;
      if (trow < 1000) {
        float4 wa = *(const float4*)&wcs[lrow][0];
        float4 wb = *(const float4*)&wcs[lrow][4];
        float wcl[8] = {wa.x, wa.y, wa.z, wa.w, wb.x, wb.y, wb.z, wb.w};
        int oc = wn + col;
        float v = acc[mt][r] + bias_s[oc];
#pragma unroll
        for (int jj = 0; jj < 8; ++jj) v = fmaf(wcl[jj], lcs[jj][oc], v);
        __builtin_nontemporal_store(
            v, &out[((size_t)(b * 1000 + trow)) * 256 + oc]);
      }
    }
}

// ---------- launch ----------
extern "C" void kernel_launch(void* const* d_in, const int* in_sizes, int n_in,
                              void* d_out, int out_size, void* d_ws, size_t ws_size,
                              hipStream_t stream) {
  const float* dur  = (const float*)d_in[0];
  const float* ph   = (const float*)d_in[1];
  const float* pjWw = (const float*)d_in[3];
  const float* pjbw = (const float*)d_in[4];
  const float* cvWw = (const float*)d_in[5];
  const float* cvbw = (const float*)d_in[6];
  const float* mlWw = (const float*)d_in[7];
  const float* mlbw = (const float*)d_in[8];
  const float* liWw = (const float*)d_in[9];
  const float* libw = (const float*)d_in[10];
  const float* pjWc = (const float*)d_in[11];
  const float* pjbc = (const float*)d_in[12];
  const float* cvWc = (const float*)d_in[13];
  const float* cvbc = (const float*)d_in[14];
  const float* mlWc = (const float*)d_in[15];
  const float* mlbc = (const float*)d_in[16];
  const float* liWc = (const float*)d_in[17];
  const float* libc = (const float*)d_in[18];
  float* out = (float*)d_out;

  float* f = (float*)d_ws;
  size_t o = 0;
  float* sk = f + o;            o += 4096;
  int* fl = (int*)(f + o);      o += 16;
  float* bK = f + o;            o += 64;
  unsigned short* Mb = (unsigned short*)(f + o); o += 6144;
  float* Lbw = f + o;           o += 16384;   // [b][l] float4 MLP bases (w)
  float* Laux = f + o;          o += 16384;   // [b][l] {bb0, bb1, msk, -}
  float* mxA = f + o;           o += 64;      // [b][4] max_l A
  _Float16* G = (_Float16*)(f + o);              o += 2097152;  // 8.4 MB
  unsigned short* phT = (unsigned short*)(f + o); o += 524288;
  unsigned short* LWT = (unsigned short*)(f + o); o += 131072;

  k_prep<<<1344, 256, 0, stream>>>(dur, ph, liWw, cvWw, pjWw, pjbw, cvWc, pjWc,
                                   pjbc, sk, fl, Mb, bK, LWT, phT);
  k_convG<<<528, 256, 0, stream>>>(phT, Mb, bK, cvbw, cvbc, dur, sk, mlWw,
                                   mlbw, mlWc, mlbc, LWT, Lbw, Laux, mxA, G);
  k_fuse<<<256, 1024, 0, stream>>>(Lbw, Laux, mxA, fl, mlWw, mlWc, G, libw,
                                   libc, liWc, out);
}